// Round 3
// baseline (611.719 us; speedup 1.0000x reference)
//
#include <hip/hip_runtime.h>
#include <hip/hip_bf16.h>
#include <stdint.h>

#define NCTX 576
#define MLAT 64
#define SEQ 640
#define DMODEL 1024
#define NH 16
#define INNER_ 1024
#define KV_W 2048

typedef float f32x4 __attribute__((ext_vector_type(4)));
typedef __bf16 bf16x8 __attribute__((ext_vector_type(8)));
typedef unsigned short u16;
typedef unsigned int u32;
typedef unsigned long long u64;

typedef __attribute__((address_space(1))) u32 as1_u32;
typedef __attribute__((address_space(3))) u32 as3_u32;

__device__ __forceinline__ u16 f2bf(float f) {
    u32 u = __builtin_bit_cast(u32, f);
    u32 r = (u + 0x7fffu + ((u >> 16) & 1u)) >> 16;
    return (u16)r;
}

// T1: bijective XCD swizzle (m204).
__device__ __forceinline__ int xcd_swizzle(int orig, int nwg) {
    int q = nwg >> 3, r = nwg & 7;
    int xcd = orig & 7, loc = orig >> 3;
    return (xcd < r ? xcd * (q + 1) : r * (q + 1) + (xcd - r) * q) + loc;
}

// ---------------- weight transpose + cast: dst[n][k] = bf16(src[k][n]) ----------------
__global__ __launch_bounds__(256) void transpose_cast(const float* __restrict__ src,
                                                      u16* __restrict__ dst, int K, int N) {
    __shared__ float tile[64][65];
    int k0 = blockIdx.y * 64, n0 = blockIdx.x * 64;
    int tid = threadIdx.x;
#pragma unroll
    for (int i = 0; i < 4; ++i) {
        int idx = i * 256 + tid;
        int kk = idx >> 4;
        int nn = (idx & 15) << 2;
        float4 v = *(const float4*)(src + (u64)(k0 + kk) * N + n0 + nn);
        tile[kk][nn] = v.x; tile[kk][nn + 1] = v.y; tile[kk][nn + 2] = v.z; tile[kk][nn + 3] = v.w;
    }
    __syncthreads();
#pragma unroll
    for (int i = 0; i < 4; ++i) {
        int idx = i * 256 + tid;
        int nn = idx >> 4;
        int kk = (idx & 15) << 2;
        ushort4 o;
        o.x = f2bf(tile[kk][nn]);     o.y = f2bf(tile[kk + 1][nn]);
        o.z = f2bf(tile[kk + 2][nn]); o.w = f2bf(tile[kk + 3][nn]);
        *(ushort4*)(dst + (u64)(n0 + nn) * K + k0 + kk) = o;
    }
}

// ---------------- fused LayerNorm -> bf16 rows of concat(xn, ln) ----------------
__global__ __launch_bounds__(256) void ln_cast(const float* __restrict__ x,
                                               const float* __restrict__ lat,
                                               const float* __restrict__ gm, const float* __restrict__ bm,
                                               const float* __restrict__ gl, const float* __restrict__ bl,
                                               u16* __restrict__ out) {
    int row = blockIdx.x;              // chunk-local: bt*640 + s
    int bt = row / SEQ, s = row - bt * SEQ;
    const float *src, *g, *b;
    if (s < NCTX) { src = x + ((u64)bt * NCTX + s) * DMODEL; g = gm; b = bm; }
    else          { src = lat + ((u64)bt * MLAT + (s - NCTX)) * DMODEL; g = gl; b = bl; }
    int tid = threadIdx.x;
    float4 v = *(const float4*)(src + tid * 4);
    float sum = v.x + v.y + v.z + v.w;
    float sq  = v.x * v.x + v.y * v.y + v.z * v.z + v.w * v.w;
#pragma unroll
    for (int off = 1; off < 64; off <<= 1) {
        sum += __shfl_xor(sum, off, 64);
        sq  += __shfl_xor(sq, off, 64);
    }
    __shared__ float red[8];
    int w = tid >> 6, lane = tid & 63;
    if (lane == 0) { red[w] = sum; red[4 + w] = sq; }
    __syncthreads();
    sum = red[0] + red[1] + red[2] + red[3];
    sq  = red[4] + red[5] + red[6] + red[7];
    float mu = sum * (1.0f / DMODEL);
    float var = sq * (1.0f / DMODEL) - mu * mu;
    float rstd = rsqrtf(var + 1e-5f);
    float4 gv = *(const float4*)(g + tid * 4);
    float4 bv = *(const float4*)(b + tid * 4);
    ushort4 o;
    o.x = f2bf((v.x - mu) * rstd * gv.x + bv.x);
    o.y = f2bf((v.y - mu) * rstd * gv.y + bv.y);
    o.z = f2bf((v.z - mu) * rstd * gv.z + bv.z);
    o.w = f2bf((v.w - mu) * rstd * gv.w + bv.w);
    *(ushort4*)(out + (u64)row * DMODEL + tid * 4) = o;
}

// ---------------- bf16 MFMA GEMM, BK=64: C[M][ldc] = A[M][1024] @ Bt[N][1024]^T ----------------
// WRITE_VT: blocks with n0 >= 1024 write output transposed per (bt,h): vt[(bt*1024 + hd)][640]
template <int WRITE_VT, typename OUT_T>
__global__ __launch_bounds__(256) void gemm_bf16(const u16* __restrict__ A,
                                                 const u16* __restrict__ Bt,
                                                 OUT_T* __restrict__ C, u16* __restrict__ vt,
                                                 int M, int ldc,
                                                 int rpgL2, long long gstride, float scale) {
    constexpr int K = 1024;
    __shared__ u16 As[128 * 64];   // 16 KB, 8-group XOR swizzle per row
    __shared__ u16 Bs[128 * 64];
    int tid = threadIdx.x;
    int lane = tid & 63;
    int w = tid >> 6;
    int wm = w >> 1, wn = w & 1;
    int nwg = gridDim.x * gridDim.y;
    int wg = xcd_swizzle(blockIdx.y * gridDim.x + blockIdx.x, nwg);
    int m0 = (wg / gridDim.x) * 128;
    int n0 = (wg % gridDim.x) * 128;
    u32 rmask = (1u << rpgL2) - 1u;

    f32x4 acc[4][4] = {};

    for (int k0 = 0; k0 < K; k0 += 64) {
        __syncthreads();
#pragma unroll
        for (int i = 0; i < 4; ++i) {
            int t = i * 256 + tid;
            int r = t >> 3;
            int cg = t & 7;
            int col = (cg ^ (r & 7)) << 3;          // pre-swizzled source column
            int grow = m0 + r; if (grow >= M) grow = M - 1;
            const u16* ga = A + (u64)(grow >> rpgL2) * (u64)gstride + (u64)(grow & rmask) * K + k0 + col;
            __builtin_amdgcn_global_load_lds((const as1_u32*)ga,
                (as3_u32*)(As + ((i * 256 + (w << 6)) << 3)), 16, 0, 0);
            const u16* gb = Bt + (u64)(n0 + r) * K + k0 + col;
            __builtin_amdgcn_global_load_lds((const as1_u32*)gb,
                (as3_u32*)(Bs + ((i * 256 + (w << 6)) << 3)), 16, 0, 0);
        }
        __syncthreads();
        int rl = lane & 15, cgl = lane >> 4;
#pragma unroll
        for (int kk = 0; kk < 2; ++kk) {
            bf16x8 a[4], b[4];
#pragma unroll
            for (int mi = 0; mi < 4; ++mi) {
                int r = wm * 64 + mi * 16 + rl;
                int g = (kk * 4 + cgl) ^ (r & 7);
                a[mi] = *(const bf16x8*)(As + r * 64 + g * 8);
            }
#pragma unroll
            for (int ni = 0; ni < 4; ++ni) {
                int r = wn * 64 + ni * 16 + rl;
                int g = (kk * 4 + cgl) ^ (r & 7);
                b[ni] = *(const bf16x8*)(Bs + r * 64 + g * 8);
            }
#pragma unroll
            for (int mi = 0; mi < 4; ++mi)
#pragma unroll
                for (int ni = 0; ni < 4; ++ni)
                    acc[mi][ni] = __builtin_amdgcn_mfma_f32_16x16x32_bf16(a[mi], b[ni], acc[mi][ni], 0, 0, 0);
        }
    }
    int rl = lane & 15, rg = lane >> 4;
    if (WRITE_VT && n0 >= INNER_) {
        // V half -> transposed store: vt[(bt*1024 + (h*64+d))][s], 4 consecutive s per ushort4
        int bt = m0 / SEQ;
        int s0 = m0 - bt * SEQ + wm * 64;
#pragma unroll
        for (int ni = 0; ni < 4; ++ni) {
            int vcol = (n0 - INNER_) + wn * 64 + ni * 16 + rl;    // h*64 + d
            u16* vrow = vt + ((u64)bt * INNER_ + vcol) * SEQ;
#pragma unroll
            for (int mi = 0; mi < 4; ++mi) {
                int s = s0 + mi * 16 + rg * 4;
                ushort4 o;
                o.x = f2bf(acc[mi][ni][0] * scale);
                o.y = f2bf(acc[mi][ni][1] * scale);
                o.z = f2bf(acc[mi][ni][2] * scale);
                o.w = f2bf(acc[mi][ni][3] * scale);
                *(ushort4*)(vrow + s) = o;
            }
        }
    } else {
#pragma unroll
        for (int mi = 0; mi < 4; ++mi) {
#pragma unroll
            for (int r = 0; r < 4; ++r) {
                int grow = m0 + wm * 64 + mi * 16 + rg * 4 + r;
                if (grow < M) {
#pragma unroll
                    for (int ni = 0; ni < 4; ++ni) {
                        int gcol = n0 + wn * 64 + ni * 16 + rl;
                        float val = acc[mi][ni][r] * scale;
                        if constexpr (sizeof(OUT_T) == 2)
                            C[(u64)grow * ldc + gcol] = (OUT_T)f2bf(val);
                        else
                            C[(u64)grow * ldc + gcol] = val;
                    }
                }
            }
        }
    }
}

// ---------------- fused flash attention per (head, bt): dbuf staging, V pre-transposed ----------------
__global__ __launch_bounds__(256) void attn_kernel(const u16* __restrict__ qb,
                                                   const u16* __restrict__ kbuf,
                                                   const u16* __restrict__ vtb,
                                                   const int* __restrict__ mask,
                                                   u16* __restrict__ ob, int bt0) {
    int h = blockIdx.x;
    int btl = blockIdx.y;
    int tid = threadIdx.x, lane = tid & 63, w = tid >> 6;
    __shared__ u16 Ks[2][64 * 64];    // [kv][dh], swizzled
    __shared__ u16 Vs[2][64 * 64];    // [dh][kv], swizzled (staged from pre-transposed vt)
    __shared__ u16 Ps[4][16 * 64];    // per-wave P
    __shared__ float bias_s[2][64];
    int rl = lane & 15, cgl = lane >> 4;

    bf16x8 aq[2];
    {
        int qr = btl * MLAT + w * 16 + rl;
        const u16* qp = qb + (u64)qr * INNER_ + h * 64 + cgl * 8;
        aq[0] = *(const bf16x8*)(qp);
        aq[1] = *(const bf16x8*)(qp + 32);
    }
    f32x4 acc[4] = {};
    float mrow[4], lrow[4];
#pragma unroll
    for (int r = 0; r < 4; ++r) { mrow[r] = -1e30f; lrow[r] = 0.f; }

    const u16* kbase = kbuf + (u64)btl * SEQ * INNER_ + h * 64;
    const u16* vbase = vtb + ((u64)btl * INNER_ + h * 64) * SEQ;

    auto stage = [&](int c, int bf) {
#pragma unroll
        for (int i = 0; i < 2; ++i) {
            int t = i * 256 + tid;
            int r = t >> 3, cg = t & 7;
            int col = (cg ^ (r & 7)) << 3;
            __builtin_amdgcn_global_load_lds((const as1_u32*)(kbase + (u64)(c * 64 + r) * INNER_ + col),
                (as3_u32*)(&Ks[bf][0] + ((i * 256 + (w << 6)) << 3)), 16, 0, 0);
            __builtin_amdgcn_global_load_lds((const as1_u32*)(vbase + (u64)r * SEQ + c * 64 + col),
                (as3_u32*)(&Vs[bf][0] + ((i * 256 + (w << 6)) << 3)), 16, 0, 0);
        }
        if (tid < 64) {
            int pos = c * 64 + tid;
            bias_s[bf][tid] = (pos < NCTX) ? ((mask[(bt0 + btl) * NCTX + pos] > 0) ? 0.f : -1e30f) : 0.f;
        }
    };

    stage(0, 0);
    __syncthreads();

    for (int c = 0; c < SEQ / 64; ++c) {
        int bf = c & 1;
        if (c + 1 < SEQ / 64) stage(c + 1, bf ^ 1);   // overlapped with compute; drained at loop-end barrier

        // S = q @ K^T (16 x 64)
        f32x4 sf[4];
#pragma unroll
        for (int ni = 0; ni < 4; ++ni) {
            f32x4 z = {};
#pragma unroll
            for (int kk = 0; kk < 2; ++kk) {
                int r = ni * 16 + rl;
                int g = (kk * 4 + cgl) ^ (r & 7);
                bf16x8 bk = *(const bf16x8*)(&Ks[bf][0] + r * 64 + g * 8);
                z = __builtin_amdgcn_mfma_f32_16x16x32_bf16(aq[kk], bk, z, 0, 0, 0);
            }
            float bias = bias_s[bf][ni * 16 + rl];
            z[0] += bias; z[1] += bias; z[2] += bias; z[3] += bias;
            sf[ni] = z;
        }
        // online softmax
        float alpha[4];
#pragma unroll
        for (int r = 0; r < 4; ++r) {
            float m = fmaxf(fmaxf(sf[0][r], sf[1][r]), fmaxf(sf[2][r], sf[3][r]));
            m = fmaxf(m, __shfl_xor(m, 1, 64));
            m = fmaxf(m, __shfl_xor(m, 2, 64));
            m = fmaxf(m, __shfl_xor(m, 4, 64));
            m = fmaxf(m, __shfl_xor(m, 8, 64));
            float mn = fmaxf(mrow[r], m);
            alpha[r] = __expf(mrow[r] - mn);
            mrow[r] = mn;
        }
#pragma unroll
        for (int ni = 0; ni < 4; ++ni)
#pragma unroll
            for (int r = 0; r < 4; ++r)
                sf[ni][r] = __expf(sf[ni][r] - mrow[r]);
#pragma unroll
        for (int r = 0; r < 4; ++r) {
            float s = sf[0][r] + sf[1][r] + sf[2][r] + sf[3][r];
            s += __shfl_xor(s, 1, 64);
            s += __shfl_xor(s, 2, 64);
            s += __shfl_xor(s, 4, 64);
            s += __shfl_xor(s, 8, 64);
            lrow[r] = lrow[r] * alpha[r] + s;
        }
        // P -> per-wave LDS (bf16, swizzled)
        u16* pw = Ps[w];
#pragma unroll
        for (int ni = 0; ni < 4; ++ni) {
#pragma unroll
            for (int r = 0; r < 4; ++r) {
                int qrow = cgl * 4 + r;
                int kcol = ni * 16 + rl;
                int cs = (((kcol >> 3) ^ (qrow & 7)) << 3) + (kcol & 7);
                pw[qrow * 64 + cs] = f2bf(sf[ni][r]);
            }
        }
#pragma unroll
        for (int oi = 0; oi < 4; ++oi)
#pragma unroll
            for (int r = 0; r < 4; ++r)
                acc[oi][r] *= alpha[r];
        // PV
        bf16x8 ap[2];
#pragma unroll
        for (int kk = 0; kk < 2; ++kk) {
            int cc = (((kk * 4 + cgl) ^ (rl & 7)) << 3);
            ap[kk] = *(const bf16x8*)(pw + rl * 64 + cc);
        }
#pragma unroll
        for (int oi = 0; oi < 4; ++oi) {
#pragma unroll
            for (int kk = 0; kk < 2; ++kk) {
                int r = oi * 16 + rl;
                int g = (kk * 4 + cgl) ^ (r & 7);
                bf16x8 bv = *(const bf16x8*)(&Vs[bf][0] + r * 64 + g * 8);
                acc[oi] = __builtin_amdgcn_mfma_f32_16x16x32_bf16(ap[kk], bv, acc[oi], 0, 0, 0);
            }
        }
        __syncthreads();
    }
    // epilogue
#pragma unroll
    for (int r = 0; r < 4; ++r) {
        float inv = 1.0f / lrow[r];
        int qrow = btl * MLAT + w * 16 + cgl * 4 + r;
        u16* op = ob + (u64)qrow * INNER_ + h * 64;
#pragma unroll
        for (int oi = 0; oi < 4; ++oi)
            op[oi * 16 + rl] = f2bf(acc[oi][r] * inv);
    }
}

// ---------------- host ----------------
extern "C" void kernel_launch(void* const* d_in, const int* in_sizes, int n_in,
                              void* d_out, int out_size, void* d_ws, size_t ws_size,
                              hipStream_t stream) {
    const float* x    = (const float*)d_in[0];
    const float* lat  = (const float*)d_in[1];
    const int*   am   = (const int*)d_in[2];
    const float* gm   = (const float*)d_in[3];
    const float* bm   = (const float*)d_in[4];
    const float* gl   = (const float*)d_in[5];
    const float* bl   = (const float*)d_in[6];
    const float* Wq   = (const float*)d_in[7];
    const float* Wkv  = (const float*)d_in[8];
    const float* Wo   = (const float*)d_in[9];
    float* out = (float*)d_out;

    u16* WqT  = (u16*)d_ws;                       // [1024][1024]
    u16* WkvT = WqT + 1024 * 1024;                // [2048][1024]
    u16* WoT  = WkvT + 2048 * 1024;               // [1024][1024]
    u16* bufs = WoT + 1024 * 1024;

    size_t fixed = (size_t)(1024 * 1024 + 2048 * 1024 + 1024 * 1024) * 2;
    // per-bt: xn 640*1024 + kbuf 640*1024 + vt 1024*640 + qb 64*1024 + ao 64*1024 elems
    size_t perbt = (size_t)(SEQ * DMODEL + SEQ * INNER_ + INNER_ * SEQ + MLAT * INNER_ + MLAT * INNER_) * 2;
    int C = 64;
    while (C > 1 && fixed + (size_t)C * perbt > ws_size) C >>= 1;

    transpose_cast<<<dim3(16, 16), 256, 0, stream>>>(Wq, WqT, 1024, 1024);
    transpose_cast<<<dim3(32, 16), 256, 0, stream>>>(Wkv, WkvT, 1024, 2048);
    transpose_cast<<<dim3(16, 16), 256, 0, stream>>>(Wo, WoT, 1024, 1024);

    for (int bt0 = 0; bt0 < 64; bt0 += C) {
        u16* xn  = bufs;
        u16* kb  = xn + (size_t)C * SEQ * DMODEL;
        u16* vtp = kb + (size_t)C * SEQ * INNER_;
        u16* qbp = vtp + (size_t)C * INNER_ * SEQ;
        u16* ao  = qbp + (size_t)C * MLAT * INNER_;

        ln_cast<<<C * SEQ, 256, 0, stream>>>(x + (u64)bt0 * NCTX * DMODEL,
                                             lat + (u64)bt0 * MLAT * DMODEL,
                                             gm, bm, gl, bl, xn);
        // kv = xn @ Wkv ; K-half row-major into kb, V-half transposed into vtp
        gemm_bf16<1, u16><<<dim3(KV_W / 128, (C * SEQ) / 128), 256, 0, stream>>>(
            xn, WkvT, kb, vtp, C * SEQ, INNER_, 30, 0, 1.0f);
        // q = ln @ Wq * 1/8  (latent rows: groups of 64 every 640)
        gemm_bf16<0, u16><<<dim3(INNER_ / 128, (C * MLAT + 127) / 128), 256, 0, stream>>>(
            xn + NCTX * DMODEL, WqT, qbp, nullptr, C * MLAT, INNER_, 6, (long long)SEQ * DMODEL, 0.125f);
        attn_kernel<<<dim3(NH, C), 256, 0, stream>>>(qbp, kb, vtp, am, ao, bt0);
        // out = ao @ Wo  -> f32
        gemm_bf16<0, float><<<dim3(DMODEL / 128, (C * MLAT + 127) / 128), 256, 0, stream>>>(
            ao, WoT, out + (u64)bt0 * MLAT * DMODEL, nullptr, C * MLAT, DMODEL, 30, 0, 1.0f);
    }
}

// Round 4
// 586.788 us; speedup vs baseline: 1.0425x; 1.0425x over previous
//
#include <hip/hip_runtime.h>
#include <hip/hip_bf16.h>
#include <stdint.h>

#define NCTX 576
#define MLAT 64
#define SEQ 640
#define DMODEL 1024
#define NH 16
#define INNER_ 1024
#define KV_W 2048

typedef float f32x4 __attribute__((ext_vector_type(4)));
typedef __bf16 bf16x8 __attribute__((ext_vector_type(8)));
typedef unsigned short u16;
typedef unsigned int u32;
typedef unsigned long long u64;

typedef __attribute__((address_space(1))) u32 as1_u32;
typedef __attribute__((address_space(3))) u32 as3_u32;

__device__ __forceinline__ u16 f2bf(float f) {
    u32 u = __builtin_bit_cast(u32, f);
    u32 r = (u + 0x7fffu + ((u >> 16) & 1u)) >> 16;
    return (u16)r;
}

// T1: bijective XCD swizzle (m204).
__device__ __forceinline__ int xcd_swizzle(int orig, int nwg) {
    int q = nwg >> 3, r = nwg & 7;
    int xcd = orig & 7, loc = orig >> 3;
    return (xcd < r ? xcd * (q + 1) : r * (q + 1) + (xcd - r) * q) + loc;
}

// ---------------- merged weight transpose + cast: dst[n][k] = bf16(src[k][n]) ----------------
// blocks 0-255: Wq (N=1024); 256-767: Wkv (N=2048); 768-1023: Wo (N=1024). K=1024 all.
__global__ __launch_bounds__(256) void transpose_cast_all(const float* __restrict__ Wq,
                                                          const float* __restrict__ Wkv,
                                                          const float* __restrict__ Wo,
                                                          u16* __restrict__ WqT,
                                                          u16* __restrict__ WkvT,
                                                          u16* __restrict__ WoT) {
    __shared__ float tile[64][65];
    int id = blockIdx.x;
    const float* src; u16* dst; int N;
    if (id < 256)      { src = Wq;  dst = WqT;  N = 1024; }
    else if (id < 768) { src = Wkv; dst = WkvT; N = 2048; id -= 256; }
    else               { src = Wo;  dst = WoT;  N = 1024; id -= 768; }
    int nx = N >> 6;
    int n0 = (id % nx) * 64, k0 = (id / nx) * 64;
    int tid = threadIdx.x;
#pragma unroll
    for (int i = 0; i < 4; ++i) {
        int idx = i * 256 + tid;
        int kk = idx >> 4;
        int nn = (idx & 15) << 2;
        float4 v = *(const float4*)(src + (u64)(k0 + kk) * N + n0 + nn);
        tile[kk][nn] = v.x; tile[kk][nn + 1] = v.y; tile[kk][nn + 2] = v.z; tile[kk][nn + 3] = v.w;
    }
    __syncthreads();
#pragma unroll
    for (int i = 0; i < 4; ++i) {
        int idx = i * 256 + tid;
        int nn = idx >> 4;
        int kk = (idx & 15) << 2;
        ushort4 o;
        o.x = f2bf(tile[kk][nn]);     o.y = f2bf(tile[kk + 1][nn]);
        o.z = f2bf(tile[kk + 2][nn]); o.w = f2bf(tile[kk + 3][nn]);
        *(ushort4*)(dst + (u64)(n0 + nn) * 1024 + k0 + kk) = o;
    }
}

// ---------------- fused LayerNorm -> bf16, one wave per row, barrier-free ----------------
__global__ __launch_bounds__(256) void ln_cast(const float* __restrict__ x,
                                               const float* __restrict__ lat,
                                               const float* __restrict__ gm, const float* __restrict__ bm,
                                               const float* __restrict__ gl, const float* __restrict__ bl,
                                               u16* __restrict__ out, int nrows) {
    int w = threadIdx.x >> 6, lane = threadIdx.x & 63;
    int nw = gridDim.x * 4;
    for (int row = blockIdx.x * 4 + w; row < nrows; row += nw) {
        int bt = row / SEQ, s = row - bt * SEQ;
        const float *src, *g, *b;
        if (s < NCTX) { src = x + ((u64)bt * NCTX + s) * DMODEL; g = gm; b = bm; }
        else          { src = lat + ((u64)bt * MLAT + (s - NCTX)) * DMODEL; g = gl; b = bl; }
        float4 v[4];
        float sum = 0.f, sq = 0.f;
#pragma unroll
        for (int j = 0; j < 4; ++j) {
            v[j] = *(const float4*)(src + ((j * 64 + lane) << 2));
            sum += v[j].x + v[j].y + v[j].z + v[j].w;
            sq  += v[j].x * v[j].x + v[j].y * v[j].y + v[j].z * v[j].z + v[j].w * v[j].w;
        }
#pragma unroll
        for (int off = 1; off < 64; off <<= 1) {
            sum += __shfl_xor(sum, off, 64);
            sq  += __shfl_xor(sq, off, 64);
        }
        float mu = sum * (1.0f / DMODEL);
        float var = sq * (1.0f / DMODEL) - mu * mu;
        float rstd = rsqrtf(var + 1e-5f);
        u16* orow = out + (u64)row * DMODEL;
#pragma unroll
        for (int j = 0; j < 4; ++j) {
            float4 gv = *(const float4*)(g + ((j * 64 + lane) << 2));
            float4 bv = *(const float4*)(b + ((j * 64 + lane) << 2));
            ushort4 o;
            o.x = f2bf((v[j].x - mu) * rstd * gv.x + bv.x);
            o.y = f2bf((v[j].y - mu) * rstd * gv.y + bv.y);
            o.z = f2bf((v[j].z - mu) * rstd * gv.z + bv.z);
            o.w = f2bf((v[j].w - mu) * rstd * gv.w + bv.w);
            *(ushort4*)(orow + ((j * 64 + lane) << 2)) = o;
        }
    }
}

// ---------------- bf16 MFMA GEMM, BK=32 (m97 structure, R2-proven) ----------------
// WRITE_VT=1: write output transposed per (bt,hd): vt[(bt*1024 + n)][640]
template <int WRITE_VT, typename OUT_T>
__global__ __launch_bounds__(256) void gemm_bf16(const u16* __restrict__ A,
                                                 const u16* __restrict__ Bt,
                                                 OUT_T* __restrict__ C, u16* __restrict__ vt,
                                                 int M, int ldc,
                                                 int rpgL2, long long gstride, float scale) {
    constexpr int K = 1024;
    __shared__ u16 As[128 * 32];
    __shared__ u16 Bs[128 * 32];
    int tid = threadIdx.x;
    int lane = tid & 63;
    int w = tid >> 6;
    int wm = w >> 1, wn = w & 1;
    int nwg = gridDim.x * gridDim.y;
    int wg = xcd_swizzle(blockIdx.y * gridDim.x + blockIdx.x, nwg);
    int m0 = (wg / gridDim.x) * 128;
    int n0 = (wg % gridDim.x) * 128;
    u32 rmask = (1u << rpgL2) - 1u;

    f32x4 acc[4][4] = {};

    for (int k0 = 0; k0 < K; k0 += 32) {
        __syncthreads();
#pragma unroll
        for (int i = 0; i < 2; ++i) {
            int t = i * 256 + tid;
            int r = t >> 2;
            int cg = t & 3;
            int col = (cg ^ ((r >> 1) & 3)) << 3;     // pre-swizzled source column
            int grow = m0 + r; if (grow >= M) grow = M - 1;
            const u16* ga = A + (u64)(grow >> rpgL2) * (u64)gstride + (u64)(grow & rmask) * K + k0 + col;
            __builtin_amdgcn_global_load_lds((const as1_u32*)ga,
                (as3_u32*)(As + ((i * 256 + (w << 6)) << 3)), 16, 0, 0);
            const u16* gb = Bt + (u64)(n0 + r) * K + k0 + col;
            __builtin_amdgcn_global_load_lds((const as1_u32*)gb,
                (as3_u32*)(Bs + ((i * 256 + (w << 6)) << 3)), 16, 0, 0);
        }
        __syncthreads();
        bf16x8 a[4], b[4];
        int rl = lane & 15;
        int cgl = lane >> 4;
#pragma unroll
        for (int mi = 0; mi < 4; ++mi) {
            int r = wm * 64 + mi * 16 + rl;
            int c = (cgl ^ ((r >> 1) & 3)) << 3;
            a[mi] = *(const bf16x8*)(As + r * 32 + c);
        }
#pragma unroll
        for (int ni = 0; ni < 4; ++ni) {
            int r = wn * 64 + ni * 16 + rl;
            int c = (cgl ^ ((r >> 1) & 3)) << 3;
            b[ni] = *(const bf16x8*)(Bs + r * 32 + c);
        }
#pragma unroll
        for (int mi = 0; mi < 4; ++mi)
#pragma unroll
            for (int ni = 0; ni < 4; ++ni)
                acc[mi][ni] = __builtin_amdgcn_mfma_f32_16x16x32_bf16(a[mi], b[ni], acc[mi][ni], 0, 0, 0);
    }
    int rl = lane & 15, rg = lane >> 4;
    if constexpr (WRITE_VT) {
        // transposed store: vt[(bt*1024 + n)][s], 4 consecutive s per ushort4
        int bt = m0 / SEQ;
        int s0 = m0 - bt * SEQ + wm * 64;
#pragma unroll
        for (int ni = 0; ni < 4; ++ni) {
            int vcol = n0 + wn * 64 + ni * 16 + rl;
            u16* vrow = vt + ((u64)bt * INNER_ + vcol) * SEQ;
#pragma unroll
            for (int mi = 0; mi < 4; ++mi) {
                int s = s0 + mi * 16 + rg * 4;
                ushort4 o;
                o.x = f2bf(acc[mi][ni][0] * scale);
                o.y = f2bf(acc[mi][ni][1] * scale);
                o.z = f2bf(acc[mi][ni][2] * scale);
                o.w = f2bf(acc[mi][ni][3] * scale);
                *(ushort4*)(vrow + s) = o;
            }
        }
    } else {
#pragma unroll
        for (int mi = 0; mi < 4; ++mi) {
#pragma unroll
            for (int r = 0; r < 4; ++r) {
                int grow = m0 + wm * 64 + mi * 16 + rg * 4 + r;
                if (grow < M) {
#pragma unroll
                    for (int ni = 0; ni < 4; ++ni) {
                        int gcol = n0 + wn * 64 + ni * 16 + rl;
                        float val = acc[mi][ni][r] * scale;
                        if constexpr (sizeof(OUT_T) == 2)
                            C[(u64)grow * ldc + gcol] = (OUT_T)f2bf(val);
                        else
                            C[(u64)grow * ldc + gcol] = val;
                    }
                }
            }
        }
    }
}

// ---------------- fused flash attention per (head, bt): dbuf staging, V pre-transposed ----------------
__global__ __launch_bounds__(256) void attn_kernel(const u16* __restrict__ qb,
                                                   const u16* __restrict__ kbuf,
                                                   const u16* __restrict__ vtb,
                                                   const int* __restrict__ mask,
                                                   u16* __restrict__ ob, int bt0) {
    int h = blockIdx.x;
    int btl = blockIdx.y;
    int tid = threadIdx.x, lane = tid & 63, w = tid >> 6;
    __shared__ u16 Ks[2][64 * 64];    // [kv][dh], swizzled
    __shared__ u16 Vs[2][64 * 64];    // [dh][kv], swizzled (staged from pre-transposed vt)
    __shared__ u16 Ps[4][16 * 64];    // per-wave P
    __shared__ float bias_s[2][64];
    int rl = lane & 15, cgl = lane >> 4;

    bf16x8 aq[2];
    {
        int qr = btl * MLAT + w * 16 + rl;
        const u16* qp = qb + (u64)qr * INNER_ + h * 64 + cgl * 8;
        aq[0] = *(const bf16x8*)(qp);
        aq[1] = *(const bf16x8*)(qp + 32);
    }
    f32x4 acc[4] = {};
    float mrow[4], lrow[4];
#pragma unroll
    for (int r = 0; r < 4; ++r) { mrow[r] = -1e30f; lrow[r] = 0.f; }

    const u16* kbase = kbuf + (u64)btl * SEQ * INNER_ + h * 64;
    const u16* vbase = vtb + ((u64)btl * INNER_ + h * 64) * SEQ;

    auto stage = [&](int c, int bf) {
#pragma unroll
        for (int i = 0; i < 2; ++i) {
            int t = i * 256 + tid;
            int r = t >> 3, cg = t & 7;
            int col = (cg ^ (r & 7)) << 3;
            __builtin_amdgcn_global_load_lds((const as1_u32*)(kbase + (u64)(c * 64 + r) * INNER_ + col),
                (as3_u32*)(&Ks[bf][0] + ((i * 256 + (w << 6)) << 3)), 16, 0, 0);
            __builtin_amdgcn_global_load_lds((const as1_u32*)(vbase + (u64)r * SEQ + c * 64 + col),
                (as3_u32*)(&Vs[bf][0] + ((i * 256 + (w << 6)) << 3)), 16, 0, 0);
        }
        if (tid < 64) {
            int pos = c * 64 + tid;
            bias_s[bf][tid] = (pos < NCTX) ? ((mask[(bt0 + btl) * NCTX + pos] > 0) ? 0.f : -1e30f) : 0.f;
        }
    };

    stage(0, 0);
    __syncthreads();

    for (int c = 0; c < SEQ / 64; ++c) {
        int bf = c & 1;
        if (c + 1 < SEQ / 64) stage(c + 1, bf ^ 1);   // overlapped with compute; drained at loop-end barrier

        // S = q @ K^T (16 x 64)
        f32x4 sf[4];
        __builtin_amdgcn_s_setprio(1);
#pragma unroll
        for (int ni = 0; ni < 4; ++ni) {
            f32x4 z = {};
#pragma unroll
            for (int kk = 0; kk < 2; ++kk) {
                int r = ni * 16 + rl;
                int g = (kk * 4 + cgl) ^ (r & 7);
                bf16x8 bk = *(const bf16x8*)(&Ks[bf][0] + r * 64 + g * 8);
                z = __builtin_amdgcn_mfma_f32_16x16x32_bf16(aq[kk], bk, z, 0, 0, 0);
            }
            float bias = bias_s[bf][ni * 16 + rl];
            z[0] += bias; z[1] += bias; z[2] += bias; z[3] += bias;
            sf[ni] = z;
        }
        __builtin_amdgcn_s_setprio(0);
        // online softmax
        float alpha[4];
#pragma unroll
        for (int r = 0; r < 4; ++r) {
            float m = fmaxf(fmaxf(sf[0][r], sf[1][r]), fmaxf(sf[2][r], sf[3][r]));
            m = fmaxf(m, __shfl_xor(m, 1, 64));
            m = fmaxf(m, __shfl_xor(m, 2, 64));
            m = fmaxf(m, __shfl_xor(m, 4, 64));
            m = fmaxf(m, __shfl_xor(m, 8, 64));
            float mn = fmaxf(mrow[r], m);
            alpha[r] = __expf(mrow[r] - mn);
            mrow[r] = mn;
        }
#pragma unroll
        for (int ni = 0; ni < 4; ++ni)
#pragma unroll
            for (int r = 0; r < 4; ++r)
                sf[ni][r] = __expf(sf[ni][r] - mrow[r]);
#pragma unroll
        for (int r = 0; r < 4; ++r) {
            float s = sf[0][r] + sf[1][r] + sf[2][r] + sf[3][r];
            s += __shfl_xor(s, 1, 64);
            s += __shfl_xor(s, 2, 64);
            s += __shfl_xor(s, 4, 64);
            s += __shfl_xor(s, 8, 64);
            lrow[r] = lrow[r] * alpha[r] + s;
        }
        // P -> per-wave LDS (bf16, swizzled)
        u16* pw = Ps[w];
#pragma unroll
        for (int ni = 0; ni < 4; ++ni) {
#pragma unroll
            for (int r = 0; r < 4; ++r) {
                int qrow = cgl * 4 + r;
                int kcol = ni * 16 + rl;
                int cs = (((kcol >> 3) ^ (qrow & 7)) << 3) + (kcol & 7);
                pw[qrow * 64 + cs] = f2bf(sf[ni][r]);
            }
        }
#pragma unroll
        for (int oi = 0; oi < 4; ++oi)
#pragma unroll
            for (int r = 0; r < 4; ++r)
                acc[oi][r] *= alpha[r];
        // PV
        bf16x8 ap[2];
#pragma unroll
        for (int kk = 0; kk < 2; ++kk) {
            int cc = (((kk * 4 + cgl) ^ (rl & 7)) << 3);
            ap[kk] = *(const bf16x8*)(pw + rl * 64 + cc);
        }
        __builtin_amdgcn_s_setprio(1);
#pragma unroll
        for (int oi = 0; oi < 4; ++oi) {
#pragma unroll
            for (int kk = 0; kk < 2; ++kk) {
                int r = oi * 16 + rl;
                int g = (kk * 4 + cgl) ^ (r & 7);
                bf16x8 bv = *(const bf16x8*)(&Vs[bf][0] + r * 64 + g * 8);
                acc[oi] = __builtin_amdgcn_mfma_f32_16x16x32_bf16(ap[kk], bv, acc[oi], 0, 0, 0);
            }
        }
        __builtin_amdgcn_s_setprio(0);
        __syncthreads();
    }
    // epilogue
#pragma unroll
    for (int r = 0; r < 4; ++r) {
        float inv = 1.0f / lrow[r];
        int qrow = btl * MLAT + w * 16 + cgl * 4 + r;
        u16* op = ob + (u64)qrow * INNER_ + h * 64;
#pragma unroll
        for (int oi = 0; oi < 4; ++oi)
            op[oi * 16 + rl] = f2bf(acc[oi][r] * inv);
    }
}

// ---------------- host ----------------
extern "C" void kernel_launch(void* const* d_in, const int* in_sizes, int n_in,
                              void* d_out, int out_size, void* d_ws, size_t ws_size,
                              hipStream_t stream) {
    const float* x    = (const float*)d_in[0];
    const float* lat  = (const float*)d_in[1];
    const int*   am   = (const int*)d_in[2];
    const float* gm   = (const float*)d_in[3];
    const float* bm   = (const float*)d_in[4];
    const float* gl   = (const float*)d_in[5];
    const float* bl   = (const float*)d_in[6];
    const float* Wq   = (const float*)d_in[7];
    const float* Wkv  = (const float*)d_in[8];
    const float* Wo   = (const float*)d_in[9];
    float* out = (float*)d_out;

    u16* WqT  = (u16*)d_ws;                       // [1024][1024]
    u16* WkvT = WqT + 1024 * 1024;                // [2048][1024]
    u16* WoT  = WkvT + 2048 * 1024;               // [1024][1024]
    u16* bufs = WoT + 1024 * 1024;

    size_t fixed = (size_t)(1024 * 1024 + 2048 * 1024 + 1024 * 1024) * 2;
    size_t perbt = (size_t)(SEQ * DMODEL + SEQ * INNER_ + INNER_ * SEQ + MLAT * INNER_ + MLAT * INNER_) * 2;
    int C = 64;
    while (C > 1 && fixed + (size_t)C * perbt > ws_size) C >>= 1;

    transpose_cast_all<<<1024, 256, 0, stream>>>(Wq, Wkv, Wo, WqT, WkvT, WoT);

    for (int bt0 = 0; bt0 < 64; bt0 += C) {
        u16* xn  = bufs;
        u16* kb  = xn + (size_t)C * SEQ * DMODEL;
        u16* vtp = kb + (size_t)C * SEQ * INNER_;
        u16* qbp = vtp + (size_t)C * INNER_ * SEQ;
        u16* ao  = qbp + (size_t)C * MLAT * INNER_;

        ln_cast<<<2048, 256, 0, stream>>>(x + (u64)bt0 * NCTX * DMODEL,
                                          lat + (u64)bt0 * MLAT * DMODEL,
                                          gm, bm, gl, bl, xn, C * SEQ);
        // K-half: kb[row][1024] = xn @ Wkv[:, :1024]
        gemm_bf16<0, u16><<<dim3(INNER_ / 128, (C * SEQ) / 128), 256, 0, stream>>>(
            xn, WkvT, kb, nullptr, C * SEQ, INNER_, 30, 0, 1.0f);
        // V-half: vt[(bt*1024+n)][640] = (xn @ Wkv[:, 1024:])^T per bt
        gemm_bf16<1, u16><<<dim3(INNER_ / 128, (C * SEQ) / 128), 256, 0, stream>>>(
            xn, WkvT + 1024 * 1024, (u16*)nullptr, vtp, C * SEQ, 0, 30, 0, 1.0f);
        // q = ln @ Wq * 1/8  (latent rows: groups of 64 every 640)
        gemm_bf16<0, u16><<<dim3(INNER_ / 128, (C * MLAT + 127) / 128), 256, 0, stream>>>(
            xn + NCTX * DMODEL, WqT, qbp, nullptr, C * MLAT, INNER_, 6, (long long)SEQ * DMODEL, 0.125f);
        attn_kernel<<<dim3(NH, C), 256, 0, stream>>>(qbp, kb, vtp, am, ao, bt0);
        // out = ao @ Wo  -> f32
        gemm_bf16<0, float><<<dim3(DMODEL / 128, (C * MLAT + 127) / 128), 256, 0, stream>>>(
            ao, WoT, out + (u64)bt0 * MLAT * DMODEL, nullptr, C * MLAT, DMODEL, 30, 0, 1.0f);
    }
}

// Round 5
// 478.027 us; speedup vs baseline: 1.2797x; 1.2275x over previous
//
#include <hip/hip_runtime.h>
#include <hip/hip_bf16.h>
#include <stdint.h>

#define NCTX 576
#define MLAT 64
#define SEQ 640
#define DMODEL 1024
#define NH 16
#define INNER_ 1024
#define KV_W 2048

typedef float f32x4 __attribute__((ext_vector_type(4)));
typedef __bf16 bf16x8 __attribute__((ext_vector_type(8)));
typedef unsigned short u16;
typedef unsigned int u32;
typedef unsigned long long u64;

typedef __attribute__((address_space(1))) u32 as1_u32;
typedef __attribute__((address_space(3))) u32 as3_u32;

__device__ __forceinline__ u16 f2bf(float f) {
    u32 u = __builtin_bit_cast(u32, f);
    u32 r = (u + 0x7fffu + ((u >> 16) & 1u)) >> 16;
    return (u16)r;
}

// T1: bijective XCD swizzle (m204).
__device__ __forceinline__ int xcd_swizzle(int orig, int nwg) {
    int q = nwg >> 3, r = nwg & 7;
    int xcd = orig & 7, loc = orig >> 3;
    return (xcd < r ? xcd * (q + 1) : r * (q + 1) + (xcd - r) * q) + loc;
}

// ---------------- mask compaction: per bt, list unmasked ctx positions then latents ----------------
// sidx[bt*640 + j] = source seq position of compact slot j (<576 ctx, >=576 latent), j < cnt[bt]
// cnt[bt] = n_unmasked + 64 ; latst[bt] = n_unmasked (slot where latents start)
__global__ __launch_bounds__(640) void build_idx(const int* __restrict__ mask,
                                                 int* __restrict__ sidx,
                                                 int* __restrict__ cnt,
                                                 int* __restrict__ latst) {
    int bt = blockIdx.x, tid = threadIdx.x;
    __shared__ int ps[640];
    int valid = (tid < NCTX) ? (mask[bt * NCTX + tid] > 0 ? 1 : 0) : 0;
    ps[tid] = valid;
    __syncthreads();
    for (int off = 1; off < 640; off <<= 1) {
        int v = (tid >= off) ? ps[tid - off] : 0;
        __syncthreads();
        ps[tid] += v;
        __syncthreads();
    }
    int nc = ps[NCTX - 1];
    if (valid) sidx[bt * SEQ + ps[tid] - 1] = tid;
    if (tid < MLAT) sidx[bt * SEQ + nc + tid] = NCTX + tid;
    if (tid == 0) { cnt[bt] = nc + MLAT; latst[bt] = nc; }
}

// ---------------- merged weight transpose + cast: dst[n][k] = bf16(src[k][n]) ----------------
__global__ __launch_bounds__(256) void transpose_cast_all(const float* __restrict__ Wq,
                                                          const float* __restrict__ Wkv,
                                                          const float* __restrict__ Wo,
                                                          u16* __restrict__ WqT,
                                                          u16* __restrict__ WkvT,
                                                          u16* __restrict__ WoT) {
    __shared__ float tile[64][65];
    int id = blockIdx.x;
    const float* src; u16* dst; int N;
    if (id < 256)      { src = Wq;  dst = WqT;  N = 1024; }
    else if (id < 768) { src = Wkv; dst = WkvT; N = 2048; id -= 256; }
    else               { src = Wo;  dst = WoT;  N = 1024; id -= 768; }
    int nx = N >> 6;
    int n0 = (id % nx) * 64, k0 = (id / nx) * 64;
    int tid = threadIdx.x;
#pragma unroll
    for (int i = 0; i < 4; ++i) {
        int idx = i * 256 + tid;
        int kk = idx >> 4;
        int nn = (idx & 15) << 2;
        float4 v = *(const float4*)(src + (u64)(k0 + kk) * N + n0 + nn);
        tile[kk][nn] = v.x; tile[kk][nn + 1] = v.y; tile[kk][nn + 2] = v.z; tile[kk][nn + 3] = v.w;
    }
    __syncthreads();
#pragma unroll
    for (int i = 0; i < 4; ++i) {
        int idx = i * 256 + tid;
        int nn = idx >> 4;
        int kk = (idx & 15) << 2;
        ushort4 o;
        o.x = f2bf(tile[kk][nn]);     o.y = f2bf(tile[kk + 1][nn]);
        o.z = f2bf(tile[kk + 2][nn]); o.w = f2bf(tile[kk + 3][nn]);
        *(ushort4*)(dst + (u64)(n0 + nn) * 1024 + k0 + kk) = o;
    }
}

// ---------------- fused LayerNorm -> bf16, gathered through compaction index ----------------
__global__ __launch_bounds__(256) void ln_cast(const float* __restrict__ x,
                                               const float* __restrict__ lat,
                                               const float* __restrict__ gm, const float* __restrict__ bm,
                                               const float* __restrict__ gl, const float* __restrict__ bl,
                                               u16* __restrict__ out,
                                               const int* __restrict__ sidx, const int* __restrict__ cnt,
                                               int bt0, int nrows) {
    int w = threadIdx.x >> 6, lane = threadIdx.x & 63;
    int nw = gridDim.x * 4;
    for (int row = blockIdx.x * 4 + w; row < nrows; row += nw) {
        int btl = row / SEQ, jl = row - btl * SEQ;
        int btg = bt0 + btl;
        if (jl >= cnt[btg]) continue;
        int sp = sidx[btg * SEQ + jl];
        const float *src, *g, *b;
        if (sp < NCTX) { src = x + ((u64)btl * NCTX + sp) * DMODEL; g = gm; b = bm; }
        else           { src = lat + ((u64)btl * MLAT + (sp - NCTX)) * DMODEL; g = gl; b = bl; }
        float4 v[4];
        float sum = 0.f, sq = 0.f;
#pragma unroll
        for (int j = 0; j < 4; ++j) {
            v[j] = *(const float4*)(src + ((j * 64 + lane) << 2));
            sum += v[j].x + v[j].y + v[j].z + v[j].w;
            sq  += v[j].x * v[j].x + v[j].y * v[j].y + v[j].z * v[j].z + v[j].w * v[j].w;
        }
#pragma unroll
        for (int off = 1; off < 64; off <<= 1) {
            sum += __shfl_xor(sum, off, 64);
            sq  += __shfl_xor(sq, off, 64);
        }
        float mu = sum * (1.0f / DMODEL);
        float var = sq * (1.0f / DMODEL) - mu * mu;
        float rstd = rsqrtf(var + 1e-5f);
        u16* orow = out + (u64)row * DMODEL;
#pragma unroll
        for (int j = 0; j < 4; ++j) {
            float4 gv = *(const float4*)(g + ((j * 64 + lane) << 2));
            float4 bv = *(const float4*)(b + ((j * 64 + lane) << 2));
            ushort4 o;
            o.x = f2bf((v[j].x - mu) * rstd * gv.x + bv.x);
            o.y = f2bf((v[j].y - mu) * rstd * gv.y + bv.y);
            o.z = f2bf((v[j].z - mu) * rstd * gv.z + bv.z);
            o.w = f2bf((v[j].w - mu) * rstd * gv.w + bv.w);
            *(ushort4*)(orow + ((j * 64 + lane) << 2)) = o;
        }
    }
}

// ---------------- bf16 MFMA GEMM, BK=32 (m97 structure, R2-proven) ----------------
// VT_SPLIT=1 (kv GEMM): blocks with n0 >= 1024 write transposed vt[(bt*1024 + n-1024)][640].
// cntp: per-bt live-row count -> dead row-tiles early-exit. latstart: latent gather (q GEMM).
template <int VT_SPLIT, typename OUT_T>
__global__ __launch_bounds__(256) void gemm_bf16(const u16* __restrict__ A,
                                                 const u16* __restrict__ Bt,
                                                 OUT_T* __restrict__ C, u16* __restrict__ vt,
                                                 int M, int ldc, float scale,
                                                 const int* __restrict__ latstart,
                                                 const int* __restrict__ cntp, int bt0) {
    constexpr int K = 1024;
    __shared__ u16 As[128 * 32];
    __shared__ u16 Bs[128 * 32];
    int tid = threadIdx.x;
    int lane = tid & 63;
    int w = tid >> 6;
    int wm = w >> 1, wn = w & 1;
    int nwg = gridDim.x * gridDim.y;
    int wg = xcd_swizzle(blockIdx.y * gridDim.x + blockIdx.x, nwg);
    int m0 = (wg / gridDim.x) * 128;
    int n0 = (wg % gridDim.x) * 128;

    int btile = m0 / SEQ;
    if (cntp) {                                   // uniform early-exit for dead row-tiles
        if (m0 - btile * SEQ >= cntp[bt0 + btile]) return;
    }

    f32x4 acc[4][4] = {};

    for (int k0 = 0; k0 < K; k0 += 32) {
        __syncthreads();
#pragma unroll
        for (int i = 0; i < 2; ++i) {
            int t = i * 256 + tid;
            int r = t >> 2;
            int cg = t & 3;
            int col = (cg ^ ((r >> 1) & 3)) << 3;     // pre-swizzled source column
            int grow = m0 + r; if (grow >= M) grow = M - 1;
            u64 row;
            if (latstart) {
                int lbt = grow >> 6;
                row = (u64)lbt * SEQ + latstart[bt0 + lbt] + (grow & 63);
            } else {
                row = (u64)grow;
            }
            const u16* ga = A + row * K + k0 + col;
            __builtin_amdgcn_global_load_lds((const as1_u32*)ga,
                (as3_u32*)(As + ((i * 256 + (w << 6)) << 3)), 16, 0, 0);
            const u16* gb = Bt + (u64)(n0 + r) * K + k0 + col;
            __builtin_amdgcn_global_load_lds((const as1_u32*)gb,
                (as3_u32*)(Bs + ((i * 256 + (w << 6)) << 3)), 16, 0, 0);
        }
        __syncthreads();
        bf16x8 a[4], b[4];
        int rl = lane & 15;
        int cgl = lane >> 4;
#pragma unroll
        for (int mi = 0; mi < 4; ++mi) {
            int r = wm * 64 + mi * 16 + rl;
            int c = (cgl ^ ((r >> 1) & 3)) << 3;
            a[mi] = *(const bf16x8*)(As + r * 32 + c);
        }
#pragma unroll
        for (int ni = 0; ni < 4; ++ni) {
            int r = wn * 64 + ni * 16 + rl;
            int c = (cgl ^ ((r >> 1) & 3)) << 3;
            b[ni] = *(const bf16x8*)(Bs + r * 32 + c);
        }
#pragma unroll
        for (int mi = 0; mi < 4; ++mi)
#pragma unroll
            for (int ni = 0; ni < 4; ++ni)
                acc[mi][ni] = __builtin_amdgcn_mfma_f32_16x16x32_bf16(a[mi], b[ni], acc[mi][ni], 0, 0, 0);
    }
    int rl = lane & 15, rg = lane >> 4;
    if (VT_SPLIT && n0 >= INNER_) {
        // V half -> transposed store: vt[(bt*1024 + (n-1024))][s], 4 consecutive s per ushort4
        int s0 = m0 - btile * SEQ + wm * 64;
#pragma unroll
        for (int ni = 0; ni < 4; ++ni) {
            int vcol = (n0 - INNER_) + wn * 64 + ni * 16 + rl;
            u16* vrow = vt + ((u64)btile * INNER_ + vcol) * SEQ;
#pragma unroll
            for (int mi = 0; mi < 4; ++mi) {
                int s = s0 + mi * 16 + rg * 4;
                ushort4 o;
                o.x = f2bf(acc[mi][ni][0] * scale);
                o.y = f2bf(acc[mi][ni][1] * scale);
                o.z = f2bf(acc[mi][ni][2] * scale);
                o.w = f2bf(acc[mi][ni][3] * scale);
                *(ushort4*)(vrow + s) = o;
            }
        }
    } else {
#pragma unroll
        for (int mi = 0; mi < 4; ++mi) {
#pragma unroll
            for (int r = 0; r < 4; ++r) {
                int grow = m0 + wm * 64 + mi * 16 + rg * 4 + r;
                if (grow < M) {
#pragma unroll
                    for (int ni = 0; ni < 4; ++ni) {
                        int gcol = n0 + wn * 64 + ni * 16 + rl;
                        float val = acc[mi][ni][r] * scale;
                        if constexpr (sizeof(OUT_T) == 2)
                            C[(u64)grow * ldc + gcol] = (OUT_T)f2bf(val);
                        else
                            C[(u64)grow * ldc + gcol] = val;
                    }
                }
            }
        }
    }
}

// ---------------- fused flash attention per (head, bt): compacted KV, dbuf staging ----------------
__global__ __launch_bounds__(256) void attn_kernel(const u16* __restrict__ qb,
                                                   const u16* __restrict__ kbuf,
                                                   const u16* __restrict__ vtb,
                                                   const int* __restrict__ cnt,
                                                   u16* __restrict__ ob, int bt0) {
    int h = blockIdx.x;
    int btl = blockIdx.y;
    int tid = threadIdx.x, lane = tid & 63, w = tid >> 6;
    __shared__ u16 Ks[2][64 * 64];    // [kv][dh], swizzled
    __shared__ u16 Vs[2][64 * 64];    // [dh][kv], swizzled (staged from pre-transposed vt)
    __shared__ u16 Ps[4][16 * 64];    // per-wave P
    __shared__ float bias_s[2][64];
    int rl = lane & 15, cgl = lane >> 4;

    int cn = cnt[bt0 + btl];
    int nch = (cn + 63) >> 6;

    bf16x8 aq[2];
    {
        int qr = btl * MLAT + w * 16 + rl;
        const u16* qp = qb + (u64)qr * INNER_ + h * 64 + cgl * 8;
        aq[0] = *(const bf16x8*)(qp);
        aq[1] = *(const bf16x8*)(qp + 32);
    }
    f32x4 acc[4] = {};
    float mrow[4], lrow[4];
#pragma unroll
    for (int r = 0; r < 4; ++r) { mrow[r] = -1e30f; lrow[r] = 0.f; }

    const u16* kbase = kbuf + (u64)btl * SEQ * INNER_ + h * 64;
    const u16* vbase = vtb + ((u64)btl * INNER_ + h * 64) * SEQ;

    auto stage = [&](int c, int bf) {
#pragma unroll
        for (int i = 0; i < 2; ++i) {
            int t = i * 256 + tid;
            int r = t >> 3, cg = t & 7;
            int col = (cg ^ (r & 7)) << 3;
            __builtin_amdgcn_global_load_lds((const as1_u32*)(kbase + (u64)(c * 64 + r) * INNER_ + col),
                (as3_u32*)(&Ks[bf][0] + ((i * 256 + (w << 6)) << 3)), 16, 0, 0);
            __builtin_amdgcn_global_load_lds((const as1_u32*)(vbase + (u64)r * SEQ + c * 64 + col),
                (as3_u32*)(&Vs[bf][0] + ((i * 256 + (w << 6)) << 3)), 16, 0, 0);
        }
        if (tid < 64) {
            int pos = c * 64 + tid;
            bias_s[bf][tid] = (pos < cn) ? 0.f : -1e30f;   // compacted: validity only
        }
    };

    stage(0, 0);
    __syncthreads();

    for (int c = 0; c < nch; ++c) {
        int bf = c & 1;
        if (c + 1 < nch) stage(c + 1, bf ^ 1);   // overlapped with compute; drained at loop-end barrier

        // S = q @ K^T (16 x 64)
        f32x4 sf[4];
        __builtin_amdgcn_s_setprio(1);
#pragma unroll
        for (int ni = 0; ni < 4; ++ni) {
            f32x4 z = {};
#pragma unroll
            for (int kk = 0; kk < 2; ++kk) {
                int r = ni * 16 + rl;
                int g = (kk * 4 + cgl) ^ (r & 7);
                bf16x8 bk = *(const bf16x8*)(&Ks[bf][0] + r * 64 + g * 8);
                z = __builtin_amdgcn_mfma_f32_16x16x32_bf16(aq[kk], bk, z, 0, 0, 0);
            }
            float bias = bias_s[bf][ni * 16 + rl];
            z[0] += bias; z[1] += bias; z[2] += bias; z[3] += bias;
            sf[ni] = z;
        }
        __builtin_amdgcn_s_setprio(0);
        // online softmax
        float alpha[4];
#pragma unroll
        for (int r = 0; r < 4; ++r) {
            float m = fmaxf(fmaxf(sf[0][r], sf[1][r]), fmaxf(sf[2][r], sf[3][r]));
            m = fmaxf(m, __shfl_xor(m, 1, 64));
            m = fmaxf(m, __shfl_xor(m, 2, 64));
            m = fmaxf(m, __shfl_xor(m, 4, 64));
            m = fmaxf(m, __shfl_xor(m, 8, 64));
            float mn = fmaxf(mrow[r], m);
            alpha[r] = __expf(mrow[r] - mn);
            mrow[r] = mn;
        }
#pragma unroll
        for (int ni = 0; ni < 4; ++ni)
#pragma unroll
            for (int r = 0; r < 4; ++r)
                sf[ni][r] = __expf(sf[ni][r] - mrow[r]);
#pragma unroll
        for (int r = 0; r < 4; ++r) {
            float s = sf[0][r] + sf[1][r] + sf[2][r] + sf[3][r];
            s += __shfl_xor(s, 1, 64);
            s += __shfl_xor(s, 2, 64);
            s += __shfl_xor(s, 4, 64);
            s += __shfl_xor(s, 8, 64);
            lrow[r] = lrow[r] * alpha[r] + s;
        }
        // P -> per-wave LDS (bf16, swizzled)
        u16* pw = Ps[w];
#pragma unroll
        for (int ni = 0; ni < 4; ++ni) {
#pragma unroll
            for (int r = 0; r < 4; ++r) {
                int qrow = cgl * 4 + r;
                int kcol = ni * 16 + rl;
                int cs = (((kcol >> 3) ^ (qrow & 7)) << 3) + (kcol & 7);
                pw[qrow * 64 + cs] = f2bf(sf[ni][r]);
            }
        }
#pragma unroll
        for (int oi = 0; oi < 4; ++oi)
#pragma unroll
            for (int r = 0; r < 4; ++r)
                acc[oi][r] *= alpha[r];
        // PV
        bf16x8 ap[2];
#pragma unroll
        for (int kk = 0; kk < 2; ++kk) {
            int cc = (((kk * 4 + cgl) ^ (rl & 7)) << 3);
            ap[kk] = *(const bf16x8*)(pw + rl * 64 + cc);
        }
        __builtin_amdgcn_s_setprio(1);
#pragma unroll
        for (int oi = 0; oi < 4; ++oi) {
#pragma unroll
            for (int kk = 0; kk < 2; ++kk) {
                int r = oi * 16 + rl;
                int g = (kk * 4 + cgl) ^ (r & 7);
                bf16x8 bv = *(const bf16x8*)(&Vs[bf][0] + r * 64 + g * 8);
                acc[oi] = __builtin_amdgcn_mfma_f32_16x16x32_bf16(ap[kk], bv, acc[oi], 0, 0, 0);
            }
        }
        __builtin_amdgcn_s_setprio(0);
        __syncthreads();
    }
    // epilogue
#pragma unroll
    for (int r = 0; r < 4; ++r) {
        float inv = 1.0f / lrow[r];
        int qrow = btl * MLAT + w * 16 + cgl * 4 + r;
        u16* op = ob + (u64)qrow * INNER_ + h * 64;
#pragma unroll
        for (int oi = 0; oi < 4; ++oi)
            op[oi * 16 + rl] = f2bf(acc[oi][r] * inv);
    }
}

// ---------------- host ----------------
extern "C" void kernel_launch(void* const* d_in, const int* in_sizes, int n_in,
                              void* d_out, int out_size, void* d_ws, size_t ws_size,
                              hipStream_t stream) {
    const float* x    = (const float*)d_in[0];
    const float* lat  = (const float*)d_in[1];
    const int*   am   = (const int*)d_in[2];
    const float* gm   = (const float*)d_in[3];
    const float* bm   = (const float*)d_in[4];
    const float* gl   = (const float*)d_in[5];
    const float* bl   = (const float*)d_in[6];
    const float* Wq   = (const float*)d_in[7];
    const float* Wkv  = (const float*)d_in[8];
    const float* Wo   = (const float*)d_in[9];
    float* out = (float*)d_out;

    // int region first (alignment), then bf16 weights, then per-chunk buffers
    int* sidx  = (int*)d_ws;                      // [64][640]
    int* cnt   = sidx + 64 * SEQ;                 // [64]
    int* latst = cnt + 64;                        // [64]
    u16* WqT   = (u16*)(latst + 64);              // [1024][1024]
    u16* WkvT  = WqT + 1024 * 1024;               // [2048][1024]
    u16* WoT   = WkvT + 2048 * 1024;              // [1024][1024]
    u16* bufs  = WoT + 1024 * 1024;

    size_t fixed = (size_t)(64 * SEQ + 128) * 4 + (size_t)(1024 * 1024 + 2048 * 1024 + 1024 * 1024) * 2;
    size_t perbt = (size_t)(SEQ * DMODEL + SEQ * INNER_ + INNER_ * SEQ + MLAT * INNER_ + MLAT * INNER_) * 2;
    int C = 64;
    while (C > 1 && fixed + (size_t)C * perbt > ws_size) C >>= 1;

    build_idx<<<64, 640, 0, stream>>>(am, sidx, cnt, latst);
    transpose_cast_all<<<1024, 256, 0, stream>>>(Wq, Wkv, Wo, WqT, WkvT, WoT);

    for (int bt0 = 0; bt0 < 64; bt0 += C) {
        u16* xn  = bufs;
        u16* kb  = xn + (size_t)C * SEQ * DMODEL;
        u16* vtp = kb + (size_t)C * SEQ * INNER_;
        u16* qbp = vtp + (size_t)C * INNER_ * SEQ;
        u16* ao  = qbp + (size_t)C * MLAT * INNER_;

        ln_cast<<<2048, 256, 0, stream>>>(x + (u64)bt0 * NCTX * DMODEL,
                                          lat + (u64)bt0 * MLAT * DMODEL,
                                          gm, bm, gl, bl, xn, sidx, cnt, bt0, C * SEQ);
        // merged kv: K-half (n0<1024) row-major into kb; V-half (n0>=1024) transposed into vtp
        gemm_bf16<1, u16><<<dim3(KV_W / 128, (C * SEQ) / 128), 256, 0, stream>>>(
            xn, WkvT, kb, vtp, C * SEQ, INNER_, 1.0f, nullptr, cnt, bt0);
        // q = ln @ Wq * 1/8 (latent rows gathered via latst)
        gemm_bf16<0, u16><<<dim3(INNER_ / 128, (C * MLAT) / 128), 256, 0, stream>>>(
            xn, WqT, qbp, nullptr, C * MLAT, INNER_, 0.125f, latst, nullptr, bt0);
        attn_kernel<<<dim3(NH, C), 256, 0, stream>>>(qbp, kb, vtp, cnt, ao, bt0);
        // out = ao @ Wo -> f32
        gemm_bf16<0, float><<<dim3(DMODEL / 128, (C * MLAT) / 128), 256, 0, stream>>>(
            ao, WoT, out + (u64)bt0 * MLAT * DMODEL, nullptr, C * MLAT, DMODEL, 1.0f, nullptr, nullptr, 0);
    }
}